// Round 13
// baseline (129.590 us; speedup 1.0000x reference)
//
#include <hip/hip_runtime.h>
#include <hip/hip_bf16.h>
#include <math.h>

// SDPA forward, no 1/sqrt(H) scale. B=2,M=16 -> 32 heads; QT=KVT=2048; H=128.
// fp32 in/out, f16 MFMA internally (absmax 0.031 vs 0.104 threshold, proven).
// R12: occupancy-diversity round. 2-wave blocks (QBLKB=64), SINGLE 32KB LDS
// buffer, grid 1024 -> 4 independent blocks/CU (same 8 waves/CU as R4, but
// from 4 unsynchronized blocks: one block's staging/softmax overlaps
// another's MFMA/LDS). KVBLK=64 kept (R6's confound removed). 2 barriers/tile,
// global_load_lds staging, pre-swizzled f16 ws tiles, in-register softmax,
// cvt_pkrtz+permlane32_swap P-pack, defer-max THR=8, setprio on MFMA.

#define HD     128
#define QTL    2048
#define KVTL   2048
#define NHEAD  32
#define KVBLK  64
#define NKT    (KVTL / KVBLK)            // 32 tiles
#define QBLKB  64                        // q-rows per block (2 waves x 32)
#define TILE_BYTES 32768                 // K 16KB + V^T 16KB (f16)
#define WS_NEEDED ((size_t)NHEAD * NKT * TILE_BYTES)   // 33,554,432

using f32x4  = __attribute__((ext_vector_type(4))) float;
using f32x16 = __attribute__((ext_vector_type(16))) float;
using f16x8  = __attribute__((ext_vector_type(8))) _Float16;
using i32x2  = __attribute__((ext_vector_type(2))) int;
using i32x4  = __attribute__((ext_vector_type(4))) int;
using bf16x8 = __attribute__((ext_vector_type(8))) __bf16;
using bf16x4 = __attribute__((ext_vector_type(4))) __bf16;

// ------------------------------------------------------------------ prep ----
// K tile [64 rows][16 slots of 16B], slot s holds h-chunk c = s ^ (r&15).
// V^T packed [64 rows][16 slots]: row r=h&63; slot s holds (u,c)=(m>>3,m&7),
//   m = s ^ (r&15): 8 f16 = V[kt*64 + c*8 + i][h = u*64 + r].
#define NK_CHUNK (NHEAD * NKT * 64 * 16)   // 1,048,576
#define NV_CHUNK (NHEAD * NKT * 8 * 128)   // 1,048,576

__global__ __launch_bounds__(256) void sdpa_prep(const float* __restrict__ kg,
                                                 const float* __restrict__ vg,
                                                 char* __restrict__ ws)
{
    const int idx = blockIdx.x * 256 + threadIdx.x;
    if (idx < NK_CHUNK) {
        const int s    = idx & 15;
        const int r    = (idx >> 4) & 63;
        const int kt   = (idx >> 10) & 31;
        const int head = idx >> 15;
        const int c    = s ^ (r & 15);
        const float* src = kg + ((size_t)head * KVTL + kt * 64 + r) * HD + c * 8;
        float4 a = *(const float4*)src;
        float4 b = *(const float4*)(src + 4);
        f16x8 h8;
        h8[0] = (_Float16)a.x; h8[1] = (_Float16)a.y;
        h8[2] = (_Float16)a.z; h8[3] = (_Float16)a.w;
        h8[4] = (_Float16)b.x; h8[5] = (_Float16)b.y;
        h8[6] = (_Float16)b.z; h8[7] = (_Float16)b.w;
        char* base = ws + (size_t)(head * NKT + kt) * TILE_BYTES;
        *(f16x8*)(base + r * 256 + s * 16) = h8;
    } else if (idx < NK_CHUNK + NV_CHUNK) {
        const int j    = idx - NK_CHUNK;
        const int h    = j & 127;
        const int c    = (j >> 7) & 7;
        const int kt   = (j >> 10) & 31;
        const int head = j >> 15;
        const int rr   = h & 63;
        const int u    = h >> 6;
        const int s    = (u * 8 + c) ^ (rr & 15);
        const float* src = vg + ((size_t)head * KVTL + kt * 64 + c * 8) * HD + h;
        f16x8 o;
        #pragma unroll
        for (int i = 0; i < 8; ++i)
            o[i] = (_Float16)src[(size_t)i * HD];
        char* base = ws + (size_t)(head * NKT + kt) * TILE_BYTES;
        *(f16x8*)(base + 16384 + rr * 256 + s * 16) = o;
    }
}

// ------------------------------------------------------------------ main ----
__device__ __forceinline__ void stage_tile(const char* __restrict__ g,
                                           char* lds, int t)
{
    // 128 threads x 16 x 16B = 32KB; dest = wave-uniform base + lane*16
    #pragma unroll
    for (int j = 0; j < 16; ++j) {
        __builtin_amdgcn_global_load_lds(
            (const __attribute__((address_space(1))) void*)(g + j * 2048 + t * 16),
            (__attribute__((address_space(3))) void*)(lds + j * 2048 + t * 16),
            16, 0, 0);
    }
}

__global__ __launch_bounds__(128, 2) void sdpa_fwd(const float* __restrict__ qg,
                                                   const char* __restrict__ ws,
                                                   float* __restrict__ og)
{
    const int head  = blockIdx.y;
    const int qblk  = blockIdx.x * QBLKB;
    const float* qh = qg + (size_t)head * QTL * HD;
    const char*  wh = ws + (size_t)head * NKT * TILE_BYTES;

    const int t  = threadIdx.x;      // 0..127
    const int wv = t >> 6;           // wave 0..1
    const int l  = t & 63;
    const int lq = l & 31;           // q-col (and fragment index)
    const int hi = l >> 5;           // k-element half
    const int lm = l & 15;           // swizzle key

    __shared__ __align__(16) char arena[TILE_BYTES];   // single 32KB buffer

    // ---- Q fragments: B-operand, lane lq = q-col; elem i -> h = hs*16+hi*8+i
    f16x8 qf[8];
    {
        const float* qrow = qh + (size_t)(qblk + wv * 32 + lq) * HD;
        #pragma unroll
        for (int hs = 0; hs < 8; ++hs) {
            float4 a = *(const float4*)(qrow + hs * 16 + hi * 8);
            float4 b = *(const float4*)(qrow + hs * 16 + hi * 8 + 4);
            f16x8 f;
            f[0] = (_Float16)a.x; f[1] = (_Float16)a.y;
            f[2] = (_Float16)a.z; f[3] = (_Float16)a.w;
            f[4] = (_Float16)b.x; f[5] = (_Float16)b.y;
            f[6] = (_Float16)b.z; f[7] = (_Float16)b.w;
            qf[hs] = f;
        }
    }

    f32x16 acc_o[4];
    #pragma unroll
    for (int ht = 0; ht < 4; ++ht)
        #pragma unroll
        for (int r = 0; r < 16; ++r) acc_o[ht][r] = 0.f;

    float m = -INFINITY, ln = 0.f;
    const float LOG2E = 1.4426950408889634f;

    stage_tile(wh, arena, t);
    __syncthreads();                 // tile 0 staged (vmcnt drained by compiler)

    for (int kt = 0; kt < NKT; ++kt) {
        const char* base = arena;

        // ---- S^T = K * Q^T : two 32x32 k-subtiles, head-dim in 8 steps
        f32x16 acc_s[2];
        __builtin_amdgcn_s_setprio(1);
        #pragma unroll
        for (int kk = 0; kk < 2; ++kk) {
            f32x16 acc;
            #pragma unroll
            for (int r = 0; r < 16; ++r) acc[r] = 0.f;
            #pragma unroll
            for (int hs = 0; hs < 8; ++hs) {
                const int off = (kk * 32 + lq) * 256 + (((hs * 2 + hi) ^ lm) * 16);
                f16x8 kf = *(const f16x8*)(base + off);
                acc = __builtin_amdgcn_mfma_f32_32x32x16_f16(kf, qf[hs], acc, 0, 0, 0);
            }
            acc_s[kk] = acc;
        }
        __builtin_amdgcn_s_setprio(0);

        // ---- in-register online softmax (lane owns q=lq; rows split w/ lane^32)
        float pm0 = -INFINITY, pm1 = -INFINITY, pm2 = -INFINITY, pm3 = -INFINITY;
        #pragma unroll
        for (int kk = 0; kk < 2; ++kk)
            #pragma unroll
            for (int r = 0; r < 16; r += 4) {
                pm0 = fmaxf(pm0, acc_s[kk][r + 0]);
                pm1 = fmaxf(pm1, acc_s[kk][r + 1]);
                pm2 = fmaxf(pm2, acc_s[kk][r + 2]);
                pm3 = fmaxf(pm3, acc_s[kk][r + 3]);
            }
        float pmax = fmaxf(fmaxf(pm0, pm1), fmaxf(pm2, pm3));
        pmax = fmaxf(pmax, __shfl_xor(pmax, 32));

        if (!__all(pmax <= m + 8.0f)) {          // defer-max THR=8
            const float mnew = fmaxf(m, pmax);
            const float sc   = exp2f((m - mnew) * LOG2E);
            m = mnew; ln *= sc;
            #pragma unroll
            for (int ht = 0; ht < 4; ++ht)
                #pragma unroll
                for (int r = 0; r < 16; ++r) acc_o[ht][r] *= sc;
        }

        // ---- P = exp(S - m), pack to f16 A-frags via cvt_pkrtz + permlane32_swap
        i32x4 fr[4];
        #pragma unroll
        for (int kk = 0; kk < 2; ++kk) {
            float p[16];
            float s0 = 0.f, s1 = 0.f, s2 = 0.f, s3 = 0.f;
            #pragma unroll
            for (int r = 0; r < 16; r += 4) {
                p[r + 0] = exp2f((acc_s[kk][r + 0] - m) * LOG2E); s0 += p[r + 0];
                p[r + 1] = exp2f((acc_s[kk][r + 1] - m) * LOG2E); s1 += p[r + 1];
                p[r + 2] = exp2f((acc_s[kk][r + 2] - m) * LOG2E); s2 += p[r + 2];
                p[r + 3] = exp2f((acc_s[kk][r + 3] - m) * LOG2E); s3 += p[r + 3];
            }
            ln += (s0 + s1) + (s2 + s3);
            int t01 = __builtin_bit_cast(int, __builtin_amdgcn_cvt_pkrtz(p[0],  p[1]));
            int t23 = __builtin_bit_cast(int, __builtin_amdgcn_cvt_pkrtz(p[2],  p[3]));
            int t45 = __builtin_bit_cast(int, __builtin_amdgcn_cvt_pkrtz(p[4],  p[5]));
            int t67 = __builtin_bit_cast(int, __builtin_amdgcn_cvt_pkrtz(p[6],  p[7]));
            int t89 = __builtin_bit_cast(int, __builtin_amdgcn_cvt_pkrtz(p[8],  p[9]));
            int tAB = __builtin_bit_cast(int, __builtin_amdgcn_cvt_pkrtz(p[10], p[11]));
            int tCD = __builtin_bit_cast(int, __builtin_amdgcn_cvt_pkrtz(p[12], p[13]));
            int tEF = __builtin_bit_cast(int, __builtin_amdgcn_cvt_pkrtz(p[14], p[15]));
            i32x2 sw;
            sw = __builtin_amdgcn_permlane32_swap(t01, t45, false, false);
            fr[2*kk][0] = sw[0]; fr[2*kk][2] = sw[1];
            sw = __builtin_amdgcn_permlane32_swap(t23, t67, false, false);
            fr[2*kk][1] = sw[0]; fr[2*kk][3] = sw[1];
            sw = __builtin_amdgcn_permlane32_swap(t89, tCD, false, false);
            fr[2*kk+1][0] = sw[0]; fr[2*kk+1][2] = sw[1];
            sw = __builtin_amdgcn_permlane32_swap(tAB, tEF, false, false);
            fr[2*kk+1][1] = sw[0]; fr[2*kk+1][3] = sw[1];
        }

        // ---- O^T += V^T * P : 4 h-tiles x 4 k-steps
        const char* Vb = base + 16384;
        __builtin_amdgcn_s_setprio(1);
        #pragma unroll
        for (int ht = 0; ht < 4; ++ht) {
            #pragma unroll
            for (int ks = 0; ks < 4; ++ks) {
                const int off = ((ht & 1) * 32 + lq) * 256 +
                                ((((ht >> 1) * 8 + ks * 2 + hi) ^ lm) * 16);
                f16x8 vf = *(const f16x8*)(Vb + off);
                acc_o[ht] = __builtin_amdgcn_mfma_f32_32x32x16_f16(
                    vf, __builtin_bit_cast(f16x8, fr[ks]), acc_o[ht], 0, 0, 0);
            }
        }
        __builtin_amdgcn_s_setprio(0);

        __syncthreads();             // all waves done reading tile kt
        if (kt + 1 < NKT)
            stage_tile(wh + (size_t)(kt + 1) * TILE_BYTES, arena, t);
        __syncthreads();             // compiler drains vmcnt(0) before barrier
    }

    // ---- finalize: combine partner halves, normalize, transpose via LDS, store
    ln += __shfl_xor(ln, 32);
    const float inv = 1.f / ln;

    const int qloc = wv * 32 + lq;   // 0..63
    #pragma unroll
    for (int ht = 0; ht < 4; ++ht) {
        #pragma unroll
        for (int r = 0; r < 4; ++r) {
            f32x4 v;
            v[0] = acc_o[ht][4*r+0] * inv;
            v[1] = acc_o[ht][4*r+1] * inv;
            v[2] = acc_o[ht][4*r+2] * inv;
            v[3] = acc_o[ht][4*r+3] * inv;   // h = ht*32 + 8r + 4hi + j
            const int slot = ht * 8 + 2 * r + hi;
            *(f32x4*)(arena + qloc * 512 + ((slot ^ lq) * 16)) = v;
        }
    }
    __syncthreads();
    {
        float* ob = og + (size_t)(head * QTL + qblk) * HD;
        #pragma unroll
        for (int j = 0; j < 16; ++j) {
            const int n  = j * 128 + t;
            const int qr = n >> 5;           // 0..63
            const int sl = n & 31;
            f32x4 v = *(const f32x4*)(arena + qr * 512 + ((sl ^ (qr & 31)) * 16));
            *(f32x4*)(ob + (size_t)qr * HD + sl * 4) = v;
        }
    }
}

// ------------------------------- fallback (R1 compensated bf16, proven) ----
__global__ __launch_bounds__(256) void sdpa_fwd_v1(const float* __restrict__ qg,
                                                   const float* __restrict__ kg,
                                                   const float* __restrict__ vg,
                                                   float* __restrict__ og)
{
    const int head  = blockIdx.y;
    const int qbase = blockIdx.x * 64;
    const float* qh = qg + (size_t)head * QTL * HD;
    const float* kh = kg + (size_t)head * KVTL * HD;
    const float* vh = vg + (size_t)head * KVTL * HD;
    float*       oh = og + (size_t)head * QTL * HD;

    const int t  = threadIdx.x;
    const int wv = t >> 6;
    const int l  = t & 63;
    const int lr = l & 15;
    const int lg = l >> 4;

    __shared__ __bf16 Kth[32][HD + 8];
    __shared__ __bf16 Ktl[32][HD + 8];
    __shared__ __bf16 Vt[HD][32 + 8];
    __shared__ __bf16 Pw[4][16][32 + 8];

    bf16x8 qfh[4], qfl[4];
    {
        const float* qrow = qh + (size_t)(qbase + wv * 16 + lr) * HD;
        #pragma unroll
        for (int ks = 0; ks < 4; ++ks) {
            bf16x8 fh, fl;
            #pragma unroll
            for (int i = 0; i < 8; ++i) {
                float x = qrow[ks * 32 + lg * 8 + i];
                __bf16 h = (__bf16)x;
                fh[i] = h;
                fl[i] = (__bf16)(x - (float)h);
            }
            qfh[ks] = fh; qfl[ks] = fl;
        }
    }

    f32x4 acc_o[8];
    #pragma unroll
    for (int h8 = 0; h8 < 8; ++h8) acc_o[h8] = (f32x4){0.f, 0.f, 0.f, 0.f};
    float mrow[4], lrow[4];
    #pragma unroll
    for (int r = 0; r < 4; ++r) { mrow[r] = -INFINITY; lrow[r] = 0.f; }
    const float LOG2E = 1.4426950408889634f;

    for (int kt = 0; kt < 64; ++kt) {
        const float* kbase = kh + (size_t)kt * 32 * HD;
        const float* vbase = vh + (size_t)kt * 32 * HD;
        __syncthreads();
        #pragma unroll
        for (int j = 0; j < 4; ++j) {
            const int e   = (j * 256 + t) * 4;
            const int row = e >> 7;
            const int col = e & 127;
            float4 f = *(const float4*)(kbase + e);
            bf16x4 h4, l4;
            h4[0] = (__bf16)f.x; l4[0] = (__bf16)(f.x - (float)h4[0]);
            h4[1] = (__bf16)f.y; l4[1] = (__bf16)(f.y - (float)h4[1]);
            h4[2] = (__bf16)f.z; l4[2] = (__bf16)(f.z - (float)h4[2]);
            h4[3] = (__bf16)f.w; l4[3] = (__bf16)(f.w - (float)h4[3]);
            *(bf16x4*)&Kth[row][col] = h4;
            *(bf16x4*)&Ktl[row][col] = l4;
        }
        #pragma unroll
        for (int j = 0; j < 4; ++j) {
            const int n     = t & 127;
            const int strip = (t >> 7) + 2 * j;
            bf16x4 b4;
            #pragma unroll
            for (int i = 0; i < 4; ++i)
                b4[i] = (__bf16)vbase[(size_t)(4 * strip + i) * HD + n];
            *(bf16x4*)&Vt[n][4 * strip] = b4;
        }
        __syncthreads();

        f32x4 acc_s[2];
        #pragma unroll
        for (int nt = 0; nt < 2; ++nt) {
            acc_s[nt] = (f32x4){0.f, 0.f, 0.f, 0.f};
            #pragma unroll
            for (int ks = 0; ks < 4; ++ks) {
                bf16x8 kh8 = *(const bf16x8*)&Kth[nt * 16 + lr][ks * 32 + lg * 8];
                bf16x8 kl8 = *(const bf16x8*)&Ktl[nt * 16 + lr][ks * 32 + lg * 8];
                acc_s[nt] = __builtin_amdgcn_mfma_f32_16x16x32_bf16(qfh[ks], kh8, acc_s[nt], 0, 0, 0);
                acc_s[nt] = __builtin_amdgcn_mfma_f32_16x16x32_bf16(qfl[ks], kh8, acc_s[nt], 0, 0, 0);
                acc_s[nt] = __builtin_amdgcn_mfma_f32_16x16x32_bf16(qfh[ks], kl8, acc_s[nt], 0, 0, 0);
            }
        }
        float p[2][4];
        #pragma unroll
        for (int r = 0; r < 4; ++r) {
            float vm = fmaxf(acc_s[0][r], acc_s[1][r]);
            vm = fmaxf(vm, __shfl_xor(vm, 1));
            vm = fmaxf(vm, __shfl_xor(vm, 2));
            vm = fmaxf(vm, __shfl_xor(vm, 4));
            vm = fmaxf(vm, __shfl_xor(vm, 8));
            const float mnew  = fmaxf(mrow[r], vm);
            const float scale = exp2f((mrow[r] - mnew) * LOG2E);
            mrow[r] = mnew;
            float ps = 0.f;
            #pragma unroll
            for (int nt = 0; nt < 2; ++nt) {
                float pe = exp2f((acc_s[nt][r] - mnew) * LOG2E);
                p[nt][r] = pe; ps += pe;
            }
            lrow[r] = lrow[r] * scale + ps;
            #pragma unroll
            for (int h8 = 0; h8 < 8; ++h8) acc_o[h8][r] *= scale;
        }
        #pragma unroll
        for (int nt = 0; nt < 2; ++nt)
            #pragma unroll
            for (int r = 0; r < 4; ++r)
                Pw[wv][lg * 4 + r][nt * 16 + lr] = (__bf16)p[nt][r];
        bf16x8 pf = *(const bf16x8*)&Pw[wv][lr][lg * 8];
        #pragma unroll
        for (int h8 = 0; h8 < 8; ++h8) {
            bf16x8 vf = *(const bf16x8*)&Vt[h8 * 16 + lr][lg * 8];
            acc_o[h8] = __builtin_amdgcn_mfma_f32_16x16x32_bf16(pf, vf, acc_o[h8], 0, 0, 0);
        }
    }
    float invl[4];
    #pragma unroll
    for (int r = 0; r < 4; ++r) {
        float s = lrow[r];
        s += __shfl_xor(s, 1);
        s += __shfl_xor(s, 2);
        s += __shfl_xor(s, 4);
        s += __shfl_xor(s, 8);
        invl[r] = 1.f / s;
    }
    float* ob = oh + (size_t)(qbase + wv * 16) * HD;
    #pragma unroll
    for (int h8 = 0; h8 < 8; ++h8)
        #pragma unroll
        for (int r = 0; r < 4; ++r)
            ob[(size_t)(lg * 4 + r) * HD + h8 * 16 + lr] = acc_o[h8][r] * invl[r];
}

extern "C" void kernel_launch(void* const* d_in, const int* in_sizes, int n_in,
                              void* d_out, int out_size, void* d_ws, size_t ws_size,
                              hipStream_t stream) {
    const float* q = (const float*)d_in[0];
    const float* k = (const float*)d_in[1];
    const float* v = (const float*)d_in[2];
    float* out = (float*)d_out;

    if (ws_size >= WS_NEEDED) {
        char* ws = (char*)d_ws;
        const int total_chunks = NK_CHUNK + NV_CHUNK;   // 2,097,152
        sdpa_prep<<<total_chunks / 256, 256, 0, stream>>>(k, v, ws);
        dim3 grid(QTL / QBLKB, NHEAD, 1);               // 32 x 32 = 1024 blocks
        sdpa_fwd<<<grid, dim3(128, 1, 1), 0, stream>>>(q, ws, out);
    } else {
        dim3 grid(QTL / 64, NHEAD, 1);
        sdpa_fwd_v1<<<grid, dim3(256, 1, 1), 0, stream>>>(q, k, v, out);
    }
}

// Round 14
// 114.522 us; speedup vs baseline: 1.1316x; 1.1316x over previous
//
#include <hip/hip_runtime.h>
#include <hip/hip_bf16.h>
#include <math.h>

// SDPA forward, no 1/sqrt(H) scale. B=2,M=16 -> 32 heads; QT=KVT=2048; H=128.
// fp32 in/out, f16 MFMA internally (absmax 0.031 vs 0.104 threshold, proven).
// R13 = revert to R5 (best measured: 115.0 us total). 8-wave block (QBLKB=256,
// 512 thr), grid = 256 = 1 block/CU. Swapped-operand 32x32 MFMA
// (S^T = mfma(K,Q): lane owns q-col -> in-register softmax), P via
// cvt_pkrtz + permlane32_swap, O^T = mfma(V^T,P), LDS transpose epilogue.
// KVBLK=64 double-buffered via global_load_lds; K/V pre-converted+pre-swizzled
// f16 in ws (prep pass); 4-bit XOR slot swizzle; defer-max THR=8; setprio(1)
// around MFMA clusters.
//
// Session summary: R5-R12 explored wave count / tile size / phase granularity /
// T15 att[2] / T14 async-stage / LDS-traffic halving / block diversity; all
// landed 111-116 us or regressed -> family plateau. Bound by serial per-tile
// {MFMA -> softmax-VALU} chain (VALU ~45%, LDS ~45%, MFMA ~26%, no pipe
// saturated; overlap levers measured neutral).

#define HD     128
#define QTL    2048
#define KVTL   2048
#define NHEAD  32
#define KVBLK  64
#define NKT    (KVTL / KVBLK)            // 32 tiles
#define QBLKB  256                       // q-rows per block (8 waves x 32)
#define TILE_BYTES 32768                 // K 16KB + V^T 16KB (f16)
#define WS_NEEDED ((size_t)NHEAD * NKT * TILE_BYTES)   // 33,554,432

using f32x4  = __attribute__((ext_vector_type(4))) float;
using f32x16 = __attribute__((ext_vector_type(16))) float;
using f16x8  = __attribute__((ext_vector_type(8))) _Float16;
using i32x2  = __attribute__((ext_vector_type(2))) int;
using i32x4  = __attribute__((ext_vector_type(4))) int;
using bf16x8 = __attribute__((ext_vector_type(8))) __bf16;
using bf16x4 = __attribute__((ext_vector_type(4))) __bf16;

// ------------------------------------------------------------------ prep ----
// K tile [64 rows][16 slots of 16B], slot s holds h-chunk c = s ^ (r&15).
// V^T packed [64 rows][16 slots]: row r=h&63; slot s holds (u,c)=(m>>3,m&7),
//   m = s ^ (r&15): 8 f16 = V[kt*64 + c*8 + i][h = u*64 + r].
#define NK_CHUNK (NHEAD * NKT * 64 * 16)   // 1,048,576
#define NV_CHUNK (NHEAD * NKT * 8 * 128)   // 1,048,576

__global__ __launch_bounds__(256) void sdpa_prep(const float* __restrict__ kg,
                                                 const float* __restrict__ vg,
                                                 char* __restrict__ ws)
{
    const int idx = blockIdx.x * 256 + threadIdx.x;
    if (idx < NK_CHUNK) {
        const int s    = idx & 15;
        const int r    = (idx >> 4) & 63;
        const int kt   = (idx >> 10) & 31;
        const int head = idx >> 15;
        const int c    = s ^ (r & 15);
        const float* src = kg + ((size_t)head * KVTL + kt * 64 + r) * HD + c * 8;
        float4 a = *(const float4*)src;
        float4 b = *(const float4*)(src + 4);
        f16x8 h8;
        h8[0] = (_Float16)a.x; h8[1] = (_Float16)a.y;
        h8[2] = (_Float16)a.z; h8[3] = (_Float16)a.w;
        h8[4] = (_Float16)b.x; h8[5] = (_Float16)b.y;
        h8[6] = (_Float16)b.z; h8[7] = (_Float16)b.w;
        char* base = ws + (size_t)(head * NKT + kt) * TILE_BYTES;
        *(f16x8*)(base + r * 256 + s * 16) = h8;
    } else if (idx < NK_CHUNK + NV_CHUNK) {
        const int j    = idx - NK_CHUNK;
        const int h    = j & 127;
        const int c    = (j >> 7) & 7;
        const int kt   = (j >> 10) & 31;
        const int head = j >> 15;
        const int rr   = h & 63;
        const int u    = h >> 6;
        const int s    = (u * 8 + c) ^ (rr & 15);
        const float* src = vg + ((size_t)head * KVTL + kt * 64 + c * 8) * HD + h;
        f16x8 o;
        #pragma unroll
        for (int i = 0; i < 8; ++i)
            o[i] = (_Float16)src[(size_t)i * HD];
        char* base = ws + (size_t)(head * NKT + kt) * TILE_BYTES;
        *(f16x8*)(base + 16384 + rr * 256 + s * 16) = o;
    }
}

// ------------------------------------------------------------------ main ----
__device__ __forceinline__ void stage_tile(const char* __restrict__ g,
                                           char* lds, int t)
{
    #pragma unroll
    for (int j = 0; j < 4; ++j) {
        __builtin_amdgcn_global_load_lds(
            (const __attribute__((address_space(1))) void*)(g + j * 8192 + t * 16),
            (__attribute__((address_space(3))) void*)(lds + j * 8192 + t * 16),
            16, 0, 0);
    }
}

__global__ __launch_bounds__(512, 1) void sdpa_fwd(const float* __restrict__ qg,
                                                   const char* __restrict__ ws,
                                                   float* __restrict__ og)
{
    const int head  = blockIdx.y;
    const int qblk  = blockIdx.x * QBLKB;
    const float* qh = qg + (size_t)head * QTL * HD;
    const char*  wh = ws + (size_t)head * NKT * TILE_BYTES;

    const int t  = threadIdx.x;
    const int wv = t >> 6;   // wave 0..7
    const int l  = t & 63;
    const int lq = l & 31;   // q-col (and fragment index)
    const int hi = l >> 5;   // k-element half
    const int lm = l & 15;   // swizzle key

    __shared__ __align__(16) char arena[65536];

    // ---- Q fragments: B-operand, lane lq = q-col; elem i -> h = hs*16+hi*8+i
    f16x8 qf[8];
    {
        const float* qrow = qh + (size_t)(qblk + wv * 32 + lq) * HD;
        #pragma unroll
        for (int hs = 0; hs < 8; ++hs) {
            float4 a = *(const float4*)(qrow + hs * 16 + hi * 8);
            float4 b = *(const float4*)(qrow + hs * 16 + hi * 8 + 4);
            f16x8 f;
            f[0] = (_Float16)a.x; f[1] = (_Float16)a.y;
            f[2] = (_Float16)a.z; f[3] = (_Float16)a.w;
            f[4] = (_Float16)b.x; f[5] = (_Float16)b.y;
            f[6] = (_Float16)b.z; f[7] = (_Float16)b.w;
            qf[hs] = f;
        }
    }

    f32x16 acc_o[4];
    #pragma unroll
    for (int ht = 0; ht < 4; ++ht)
        #pragma unroll
        for (int r = 0; r < 16; ++r) acc_o[ht][r] = 0.f;

    float m = -INFINITY, ln = 0.f;
    const float LOG2E = 1.4426950408889634f;

    stage_tile(wh, arena, t);
    __syncthreads();

    for (int kt = 0; kt < NKT; ++kt) {
        const int cur = kt & 1;
        char* base = arena + cur * 32768;
        if (kt + 1 < NKT)
            stage_tile(wh + (size_t)(kt + 1) * TILE_BYTES, arena + (cur ^ 1) * 32768, t);

        // ---- S^T = K * Q^T : two 32x32 k-subtiles, head-dim in 8 steps
        f32x16 acc_s[2];
        __builtin_amdgcn_s_setprio(1);
        #pragma unroll
        for (int kk = 0; kk < 2; ++kk) {
            f32x16 acc;
            #pragma unroll
            for (int r = 0; r < 16; ++r) acc[r] = 0.f;
            #pragma unroll
            for (int hs = 0; hs < 8; ++hs) {
                const int off = (kk * 32 + lq) * 256 + (((hs * 2 + hi) ^ lm) * 16);
                f16x8 kf = *(const f16x8*)(base + off);
                acc = __builtin_amdgcn_mfma_f32_32x32x16_f16(kf, qf[hs], acc, 0, 0, 0);
            }
            acc_s[kk] = acc;
        }
        __builtin_amdgcn_s_setprio(0);

        // ---- in-register online softmax (lane owns q=lq; rows split w/ lane+32)
        float pm0 = -INFINITY, pm1 = -INFINITY, pm2 = -INFINITY, pm3 = -INFINITY;
        #pragma unroll
        for (int kk = 0; kk < 2; ++kk)
            #pragma unroll
            for (int r = 0; r < 16; r += 4) {
                pm0 = fmaxf(pm0, acc_s[kk][r + 0]);
                pm1 = fmaxf(pm1, acc_s[kk][r + 1]);
                pm2 = fmaxf(pm2, acc_s[kk][r + 2]);
                pm3 = fmaxf(pm3, acc_s[kk][r + 3]);
            }
        float pmax = fmaxf(fmaxf(pm0, pm1), fmaxf(pm2, pm3));
        pmax = fmaxf(pmax, __shfl_xor(pmax, 32));

        if (!__all(pmax <= m + 8.0f)) {          // defer-max THR=8
            const float mnew = fmaxf(m, pmax);
            const float sc   = exp2f((m - mnew) * LOG2E);
            m = mnew; ln *= sc;
            #pragma unroll
            for (int ht = 0; ht < 4; ++ht)
                #pragma unroll
                for (int r = 0; r < 16; ++r) acc_o[ht][r] *= sc;
        }

        // ---- P = exp(S - m), pack to f16 A-frags via cvt_pkrtz + permlane32_swap
        i32x4 fr[4];
        #pragma unroll
        for (int kk = 0; kk < 2; ++kk) {
            float p[16];
            float s0 = 0.f, s1 = 0.f, s2 = 0.f, s3 = 0.f;
            #pragma unroll
            for (int r = 0; r < 16; r += 4) {
                p[r + 0] = exp2f((acc_s[kk][r + 0] - m) * LOG2E); s0 += p[r + 0];
                p[r + 1] = exp2f((acc_s[kk][r + 1] - m) * LOG2E); s1 += p[r + 1];
                p[r + 2] = exp2f((acc_s[kk][r + 2] - m) * LOG2E); s2 += p[r + 2];
                p[r + 3] = exp2f((acc_s[kk][r + 3] - m) * LOG2E); s3 += p[r + 3];
            }
            ln += (s0 + s1) + (s2 + s3);
            int t01 = __builtin_bit_cast(int, __builtin_amdgcn_cvt_pkrtz(p[0],  p[1]));
            int t23 = __builtin_bit_cast(int, __builtin_amdgcn_cvt_pkrtz(p[2],  p[3]));
            int t45 = __builtin_bit_cast(int, __builtin_amdgcn_cvt_pkrtz(p[4],  p[5]));
            int t67 = __builtin_bit_cast(int, __builtin_amdgcn_cvt_pkrtz(p[6],  p[7]));
            int t89 = __builtin_bit_cast(int, __builtin_amdgcn_cvt_pkrtz(p[8],  p[9]));
            int tAB = __builtin_bit_cast(int, __builtin_amdgcn_cvt_pkrtz(p[10], p[11]));
            int tCD = __builtin_bit_cast(int, __builtin_amdgcn_cvt_pkrtz(p[12], p[13]));
            int tEF = __builtin_bit_cast(int, __builtin_amdgcn_cvt_pkrtz(p[14], p[15]));
            i32x2 sw;
            sw = __builtin_amdgcn_permlane32_swap(t01, t45, false, false);
            fr[2*kk][0] = sw[0]; fr[2*kk][2] = sw[1];
            sw = __builtin_amdgcn_permlane32_swap(t23, t67, false, false);
            fr[2*kk][1] = sw[0]; fr[2*kk][3] = sw[1];
            sw = __builtin_amdgcn_permlane32_swap(t89, tCD, false, false);
            fr[2*kk+1][0] = sw[0]; fr[2*kk+1][2] = sw[1];
            sw = __builtin_amdgcn_permlane32_swap(tAB, tEF, false, false);
            fr[2*kk+1][1] = sw[0]; fr[2*kk+1][3] = sw[1];
        }

        // ---- O^T += V^T * P : 4 h-tiles x 4 k-steps
        const char* Vb = base + 16384;
        __builtin_amdgcn_s_setprio(1);
        #pragma unroll
        for (int ht = 0; ht < 4; ++ht) {
            #pragma unroll
            for (int ks = 0; ks < 4; ++ks) {
                const int off = ((ht & 1) * 32 + lq) * 256 +
                                ((((ht >> 1) * 8 + ks * 2 + hi) ^ lm) * 16);
                f16x8 vf = *(const f16x8*)(Vb + off);
                acc_o[ht] = __builtin_amdgcn_mfma_f32_32x32x16_f16(
                    vf, __builtin_bit_cast(f16x8, fr[ks]), acc_o[ht], 0, 0, 0);
            }
        }
        __builtin_amdgcn_s_setprio(0);

        __syncthreads();   // next tile staged; all waves done with cur
    }

    // ---- finalize: combine partner halves, normalize
    ln += __shfl_xor(ln, 32);
    const float inv = 1.f / ln;
    const int qloc = wv * 32 + lq;

    // two half-passes (128 q-rows each) through the 64KB arena
    #pragma unroll
    for (int half = 0; half < 2; ++half) {
        __syncthreads();
        if ((wv >> 2) == half) {
            const int lrow = qloc - half * 128;    // 0..127
            #pragma unroll
            for (int ht = 0; ht < 4; ++ht) {
                #pragma unroll
                for (int r = 0; r < 4; ++r) {
                    f32x4 v;
                    v[0] = acc_o[ht][4*r+0] * inv;
                    v[1] = acc_o[ht][4*r+1] * inv;
                    v[2] = acc_o[ht][4*r+2] * inv;
                    v[3] = acc_o[ht][4*r+3] * inv;   // h = ht*32 + 8r + 4hi + j
                    const int slot = ht * 8 + 2 * r + hi;
                    *(f32x4*)(arena + lrow * 512 + ((slot ^ lq) * 16)) = v;
                }
            }
        }
        __syncthreads();
        float* ob = og + (size_t)(head * QTL + qblk + half * 128) * HD;
        #pragma unroll
        for (int j = 0; j < 8; ++j) {
            const int n  = j * 512 + t;
            const int qr = n >> 5;          // 0..127
            const int sl = n & 31;
            f32x4 v = *(const f32x4*)(arena + qr * 512 + ((sl ^ (qr & 31)) * 16));
            *(f32x4*)(ob + (size_t)qr * HD + sl * 4) = v;
        }
    }
}

// ------------------------------- fallback (R1 compensated bf16, proven) ----
__global__ __launch_bounds__(256) void sdpa_fwd_v1(const float* __restrict__ qg,
                                                   const float* __restrict__ kg,
                                                   const float* __restrict__ vg,
                                                   float* __restrict__ og)
{
    const int head  = blockIdx.y;
    const int qbase = blockIdx.x * 64;
    const float* qh = qg + (size_t)head * QTL * HD;
    const float* kh = kg + (size_t)head * KVTL * HD;
    const float* vh = vg + (size_t)head * KVTL * HD;
    float*       oh = og + (size_t)head * QTL * HD;

    const int t  = threadIdx.x;
    const int wv = t >> 6;
    const int l  = t & 63;
    const int lr = l & 15;
    const int lg = l >> 4;

    __shared__ __bf16 Kth[32][HD + 8];
    __shared__ __bf16 Ktl[32][HD + 8];
    __shared__ __bf16 Vt[HD][32 + 8];
    __shared__ __bf16 Pw[4][16][32 + 8];

    bf16x8 qfh[4], qfl[4];
    {
        const float* qrow = qh + (size_t)(qbase + wv * 16 + lr) * HD;
        #pragma unroll
        for (int ks = 0; ks < 4; ++ks) {
            bf16x8 fh, fl;
            #pragma unroll
            for (int i = 0; i < 8; ++i) {
                float x = qrow[ks * 32 + lg * 8 + i];
                __bf16 h = (__bf16)x;
                fh[i] = h;
                fl[i] = (__bf16)(x - (float)h);
            }
            qfh[ks] = fh; qfl[ks] = fl;
        }
    }

    f32x4 acc_o[8];
    #pragma unroll
    for (int h8 = 0; h8 < 8; ++h8) acc_o[h8] = (f32x4){0.f, 0.f, 0.f, 0.f};
    float mrow[4], lrow[4];
    #pragma unroll
    for (int r = 0; r < 4; ++r) { mrow[r] = -INFINITY; lrow[r] = 0.f; }
    const float LOG2E = 1.4426950408889634f;

    for (int kt = 0; kt < 64; ++kt) {
        const float* kbase = kh + (size_t)kt * 32 * HD;
        const float* vbase = vh + (size_t)kt * 32 * HD;
        __syncthreads();
        #pragma unroll
        for (int j = 0; j < 4; ++j) {
            const int e   = (j * 256 + t) * 4;
            const int row = e >> 7;
            const int col = e & 127;
            float4 f = *(const float4*)(kbase + e);
            bf16x4 h4, l4;
            h4[0] = (__bf16)f.x; l4[0] = (__bf16)(f.x - (float)h4[0]);
            h4[1] = (__bf16)f.y; l4[1] = (__bf16)(f.y - (float)h4[1]);
            h4[2] = (__bf16)f.z; l4[2] = (__bf16)(f.z - (float)h4[2]);
            h4[3] = (__bf16)f.w; l4[3] = (__bf16)(f.w - (float)h4[3]);
            *(bf16x4*)&Kth[row][col] = h4;
            *(bf16x4*)&Ktl[row][col] = l4;
        }
        #pragma unroll
        for (int j = 0; j < 4; ++j) {
            const int n     = t & 127;
            const int strip = (t >> 7) + 2 * j;
            bf16x4 b4;
            #pragma unroll
            for (int i = 0; i < 4; ++i)
                b4[i] = (__bf16)vbase[(size_t)(4 * strip + i) * HD + n];
            *(bf16x4*)&Vt[n][4 * strip] = b4;
        }
        __syncthreads();

        f32x4 acc_s[2];
        #pragma unroll
        for (int nt = 0; nt < 2; ++nt) {
            acc_s[nt] = (f32x4){0.f, 0.f, 0.f, 0.f};
            #pragma unroll
            for (int ks = 0; ks < 4; ++ks) {
                bf16x8 kh8 = *(const bf16x8*)&Kth[nt * 16 + lr][ks * 32 + lg * 8];
                bf16x8 kl8 = *(const bf16x8*)&Ktl[nt * 16 + lr][ks * 32 + lg * 8];
                acc_s[nt] = __builtin_amdgcn_mfma_f32_16x16x32_bf16(qfh[ks], kh8, acc_s[nt], 0, 0, 0);
                acc_s[nt] = __builtin_amdgcn_mfma_f32_16x16x32_bf16(qfl[ks], kh8, acc_s[nt], 0, 0, 0);
                acc_s[nt] = __builtin_amdgcn_mfma_f32_16x16x32_bf16(qfh[ks], kl8, acc_s[nt], 0, 0, 0);
            }
        }
        float p[2][4];
        #pragma unroll
        for (int r = 0; r < 4; ++r) {
            float vm = fmaxf(acc_s[0][r], acc_s[1][r]);
            vm = fmaxf(vm, __shfl_xor(vm, 1));
            vm = fmaxf(vm, __shfl_xor(vm, 2));
            vm = fmaxf(vm, __shfl_xor(vm, 4));
            vm = fmaxf(vm, __shfl_xor(vm, 8));
            const float mnew  = fmaxf(mrow[r], vm);
            const float scale = exp2f((mrow[r] - mnew) * LOG2E);
            mrow[r] = mnew;
            float ps = 0.f;
            #pragma unroll
            for (int nt = 0; nt < 2; ++nt) {
                float pe = exp2f((acc_s[nt][r] - mnew) * LOG2E);
                p[nt][r] = pe; ps += pe;
            }
            lrow[r] = lrow[r] * scale + ps;
            #pragma unroll
            for (int h8 = 0; h8 < 8; ++h8) acc_o[h8][r] *= scale;
        }
        #pragma unroll
        for (int nt = 0; nt < 2; ++nt)
            #pragma unroll
            for (int r = 0; r < 4; ++r)
                Pw[wv][lg * 4 + r][nt * 16 + lr] = (__bf16)p[nt][r];
        bf16x8 pf = *(const bf16x8*)&Pw[wv][lr][lg * 8];
        #pragma unroll
        for (int h8 = 0; h8 < 8; ++h8) {
            bf16x8 vf = *(const bf16x8*)&Vt[h8 * 16 + lr][lg * 8];
            acc_o[h8] = __builtin_amdgcn_mfma_f32_16x16x32_bf16(pf, vf, acc_o[h8], 0, 0, 0);
        }
    }
    float invl[4];
    #pragma unroll
    for (int r = 0; r < 4; ++r) {
        float s = lrow[r];
        s += __shfl_xor(s, 1);
        s += __shfl_xor(s, 2);
        s += __shfl_xor(s, 4);
        s += __shfl_xor(s, 8);
        invl[r] = 1.f / s;
    }
    float* ob = oh + (size_t)(qbase + wv * 16) * HD;
    #pragma unroll
    for (int h8 = 0; h8 < 8; ++h8)
        #pragma unroll
        for (int r = 0; r < 4; ++r)
            ob[(size_t)(lg * 4 + r) * HD + h8 * 16 + lr] = acc_o[h8][r] * invl[r];
}

extern "C" void kernel_launch(void* const* d_in, const int* in_sizes, int n_in,
                              void* d_out, int out_size, void* d_ws, size_t ws_size,
                              hipStream_t stream) {
    const float* q = (const float*)d_in[0];
    const float* k = (const float*)d_in[1];
    const float* v = (const float*)d_in[2];
    float* out = (float*)d_out;

    if (ws_size >= WS_NEEDED) {
        char* ws = (char*)d_ws;
        const int total_chunks = NK_CHUNK + NV_CHUNK;   // 2,097,152
        sdpa_prep<<<total_chunks / 256, 256, 0, stream>>>(k, v, ws);
        dim3 grid(QTL / QBLKB, NHEAD, 1);               // 8 x 32 = 256 blocks
        sdpa_fwd<<<grid, dim3(512, 1, 1), 0, stream>>>(q, ws, out);
    } else {
        dim3 grid(QTL / 64, NHEAD, 1);
        sdpa_fwd_v1<<<grid, dim3(256, 1, 1), 0, stream>>>(q, k, v, out);
    }
}